// Round 8
// baseline (957.515 us; speedup 1.0000x reference)
//
#include <hip/hip_runtime.h>

// B=512, T-1=128, D=128, H=512. softmax(proj_x + shift[:,None]) == softmax(proj_x)
// => attention is timestep-invariant; only the LSTM recurrence is sequential.
//
// R8 = R3's PROVEN skeleton (bid groups, MALL sc0 sc1 hand-off, LDS-staged h)
// + three intra-block deltas:
//  (1) poll at loop BOTTOM by idle kh=1 wave (overlaps own pointwise+flag tail)
//  (2) rt x kh wave grid: 1 A-read feeds 4 MFMAs; acc holds all 4 gates of a
//      cell => GT exchange = kh-partials only (half traffic), barrier (d) gone
//      (per-wave flags, poller checks 4 dwords/block via one dwordx4)
//  (3) wi-MFMAs at loop top; W_ih via LDS tile; bh[8][4] in regs (~232 regs,
//      no spill; R5's regression was ~272-reg scratch spill).

typedef __attribute__((ext_vector_type(8))) short short8;
typedef __attribute__((ext_vector_type(4))) float floatx4;
typedef __attribute__((ext_vector_type(4))) unsigned int uintx4;

#define NB 512
#define NT 128
#define ND 128
#define NH 512

// LDS layout
#define HH_OFF 0          // h tile [64][512] bf16 swizzled (64 KB)
#define WT_OFF 65536      // wi tile [64][128] bf16 swizzled (16 KB)
#define WI_OFF 81920      // W_ih slice [64][128] bf16 swizzled (16 KB)
#define GT_OFF 98304      // kh=1 gate partials [64][66] f32 (16896 B)
#define LDS_BYTES 115200  // > 81920 => 1 block/CU

static __device__ __forceinline__ unsigned short f2bf(float f) {
  unsigned int u = __float_as_uint(f);
  u += 0x7fffu + ((u >> 16) & 1u);   // RNE
  return (unsigned short)(u >> 16);
}
static __device__ __forceinline__ float sigf(float x) {
  return 1.f / (1.f + __expf(-x));
}
static __device__ __forceinline__ float tanh_fast(float x) {
  const float e = __expf(-2.f * fabsf(x));
  const float r = (1.f - e) / (1.f + e);
  return copysignf(r, x);
}

// ---------------------------------------------------------------------------
// Kernel A: attn[b,d] = softmax_d( sum_t in[b,t,d]*wx[t] ); out0 = attn*in
// ---------------------------------------------------------------------------
__global__ __launch_bounds__(128) void attn_kernel(
    const float* __restrict__ in, const float* __restrict__ attn_W,
    float* __restrict__ out0, float* __restrict__ attn_ws) {
  const int b = blockIdx.x;
  const int d = threadIdx.x;
  __shared__ float wx[NT];
  __shared__ float red[4];
  wx[d] = attn_W[2 * NH + d];
  __syncthreads();
  const float* ib = in + (size_t)b * (NT * ND);
  float p = 0.f;
#pragma unroll 8
  for (int t = 0; t < NT; ++t) p = fmaf(ib[t * ND + d], wx[t], p);
  float m = p;
#pragma unroll
  for (int off = 32; off >= 1; off >>= 1) m = fmaxf(m, __shfl_xor(m, off));
  const int wv = d >> 6;
  if ((d & 63) == 0) red[wv] = m;
  __syncthreads();
  const float M = fmaxf(red[0], red[1]);
  const float e = expf(p - M);
  float s = e;
#pragma unroll
  for (int off = 32; off >= 1; off >>= 1) s += __shfl_xor(s, off);
  if ((d & 63) == 0) red[2 + wv] = s;
  __syncthreads();
  const float a = e / (red[2] + red[3]);
  attn_ws[b * ND + d] = a;
#pragma unroll 4
  for (int t = 0; t < NT; ++t)
    out0[(size_t)b * (NT * ND) + t * ND + d] = a * ib[t * ND + d];
}

// ---------------------------------------------------------------------------
// Kernel C: persistent fused LSTM recurrence. 256 blocks x 512 thr, 1/CU.
// Block (gid=bid&7, sid=bid>>3): batch rows [gid*64,+64), h-cols [sid*16,+16).
// Wave wid: rt=wid&3 (16-row tile), kh=wid>>2 (K half). acc[ct] = gate ct for
// cell (row = rt*16+kg*4+r, col = n0+colB): all 4 gates in one lane.
// ---------------------------------------------------------------------------
__global__ __launch_bounds__(512, 2) void rec_kernel(
    const float* __restrict__ in, const float* __restrict__ W_ih,
    const float* __restrict__ W_hh, const float* __restrict__ b_ih,
    const float* __restrict__ b_hh, const float* __restrict__ attn_ws,
    unsigned short* __restrict__ hbuf, unsigned int* __restrict__ flags,
    float* __restrict__ out1) {
  __shared__ __align__(16) unsigned char LDS[LDS_BYTES];
  const int tid = threadIdx.x;
  const int bid = blockIdx.x;
  const int gid = bid & 7;
  const int sid = bid >> 3;
  const int bb0 = gid * 64;
  const int n0 = sid * 16;
  const int lane = tid & 63;
  const int wid = tid >> 6;
  const int rt = wid & 3;
  const int kh = wid >> 2;
  const int colB = lane & 15;
  const int kg = lane >> 4;
  const int swB = (colB & 7) << 4;

  // ---- W_hh fragments -> registers (128 regs) ----
  short8 bh[8][4];
#pragma unroll
  for (int ct = 0; ct < 4; ++ct) {
    const float* wr_h = W_hh + (size_t)(ct * NH + n0 + colB) * NH + kh * 256;
#pragma unroll
    for (int ksl = 0; ksl < 8; ++ksl) {
      const int k0 = ksl * 32 + kg * 8;
      floatx4 f0 = *(const floatx4*)(wr_h + k0);
      floatx4 f1 = *(const floatx4*)(wr_h + k0 + 4);
      short8 s;
#pragma unroll
      for (int i = 0; i < 4; ++i) {
        s[i] = (short)f2bf(f0[i]);
        s[4 + i] = (short)f2bf(f1[i]);
      }
      bh[ksl][ct] = s;
    }
  }
  // ---- W_ih slice -> LDS tile [64][128] bf16 swizzled ----
#pragma unroll 4
  for (int it = 0; it < 16; ++it) {
    const int jj = it * 4 + (tid >> 7);            // 0..63 = ct*16 + col
    const int k = tid & 127;
    const int j = (jj >> 4) * NH + n0 + (jj & 15);
    *(unsigned short*)&LDS[WI_OFF + jj * 256 + ((2 * k) ^ ((jj & 7) << 4))] =
        f2bf(W_ih[j * ND + k]);
  }

  // ---- attention packed (t-invariant), rA/pA staging layout ----
  const int rA = tid >> 3;
  const int pA = tid & 7;
  unsigned int apk[8];
  {
    const float* ap = attn_ws + (size_t)(bb0 + rA) * ND + pA * 16;
#pragma unroll
    for (int p = 0; p < 8; ++p)
      apk[p] = (unsigned int)f2bf(ap[2 * p]) |
               ((unsigned int)f2bf(ap[2 * p + 1]) << 16);
  }

  // ---- biases for this lane's gate-col ----
  const int jC2 = n0 + colB;
  const float bi_i = b_ih[jC2] + b_hh[jC2];
  const float bi_f = b_ih[NH + jC2] + b_hh[NH + jC2];
  const float bi_g = b_ih[2 * NH + jC2] + b_hh[2 * NH + jC2];
  const float bi_o = b_ih[3 * NH + jC2] + b_hh[3 * NH + jC2];
  float c0 = 0.f, c1 = 0.f, c2 = 0.f, c3 = 0.f;

  unsigned int* fblk = flags + (gid * 32 + sid) * 16;           // 64B region
  const unsigned int* fpoll = flags + (gid * 32 + (lane & 31)) * 16;

  const float* xrow = in + (size_t)(bb0 + rA) * (NT * ND) + pA * 16;

  // ---- prologue: WT <- wi_0; xr4 <- x_1 ----
  floatx4 xr4[4];
  {
#pragma unroll
    for (int q = 0; q < 4; ++q) xr4[q] = *(const floatx4*)(xrow + 4 * q);
    unsigned int w[8];
#pragma unroll
    for (int p = 0; p < 8; ++p) {
      const float a0 = __uint_as_float(apk[p] << 16);
      const float a1 = __uint_as_float(apk[p] & 0xffff0000u);
      w[p] = (unsigned int)f2bf(a0 * xr4[p >> 1][(p & 1) * 2 + 0]) |
             ((unsigned int)f2bf(a1 * xr4[p >> 1][(p & 1) * 2 + 1]) << 16);
    }
    const int base = WT_OFF + rA * 256;
    const int swp = (rA & 7) << 4;
    uintx4 lo = {w[0], w[1], w[2], w[3]};
    uintx4 hi = {w[4], w[5], w[6], w[7]};
    *(uintx4*)&LDS[base + ((pA * 32) ^ swp)] = lo;
    *(uintx4*)&LDS[base + ((pA * 32 + 16) ^ swp)] = hi;
#pragma unroll
    for (int q = 0; q < 4; ++q) xr4[q] = *(const floatx4*)(xrow + ND + 4 * q);
  }
  __syncthreads();

  for (int t = 0; t < NT; ++t) {
    // ======== wi MFMAs (step t) from WT + WI ========
    floatx4 acc[4];
#pragma unroll
    for (int ct = 0; ct < 4; ++ct) acc[ct] = {0.f, 0.f, 0.f, 0.f};
#pragma unroll
    for (int ksl = 0; ksl < 2; ++ksl) {
      const int k2 = kh * 128 + ksl * 64 + kg * 16;
      short8 aA = *(const short8*)&LDS[WT_OFF + (rt * 16 + colB) * 256 + (k2 ^ swB)];
      short8 b0 = *(const short8*)&LDS[WI_OFF + (0 * 16 + colB) * 256 + (k2 ^ swB)];
      short8 b1 = *(const short8*)&LDS[WI_OFF + (1 * 16 + colB) * 256 + (k2 ^ swB)];
      short8 b2 = *(const short8*)&LDS[WI_OFF + (2 * 16 + colB) * 256 + (k2 ^ swB)];
      short8 b3 = *(const short8*)&LDS[WI_OFF + (3 * 16 + colB) * 256 + (k2 ^ swB)];
      acc[0] = __builtin_amdgcn_mfma_f32_16x16x32_bf16(aA, b0, acc[0], 0, 0, 0);
      acc[1] = __builtin_amdgcn_mfma_f32_16x16x32_bf16(aA, b1, acc[1], 0, 0, 0);
      acc[2] = __builtin_amdgcn_mfma_f32_16x16x32_bf16(aA, b2, acc[2], 0, 0, 0);
      acc[3] = __builtin_amdgcn_mfma_f32_16x16x32_bf16(aA, b3, acc[3], 0, 0, 0);
    }
    // ======== pack wi_{t+1} (frees xr4 before hq goes live) ========
    unsigned int w[8];
#pragma unroll
    for (int p = 0; p < 8; ++p) {
      const float a0 = __uint_as_float(apk[p] << 16);
      const float a1 = __uint_as_float(apk[p] & 0xffff0000u);
      w[p] = (unsigned int)f2bf(a0 * xr4[p >> 1][(p & 1) * 2 + 0]) |
             ((unsigned int)f2bf(a1 * xr4[p >> 1][(p & 1) * 2 + 1]) << 16);
    }
    // ======== h gather + LDS stage (t>0); flags>=t guaranteed by (a) ========
    if (t > 0) {
      const char* hb = (const char*)hbuf + ((t & 1) ? (size_t)(NB * NH) * 2 : 0) +
                       (size_t)(bb0 + wid * 8) * NH * 2 + lane * 16;
      const char* hb2 = hb + 4096;
      uintx4 hq0, hq1, hq2, hq3, hq4, hq5, hq6, hq7;
      asm volatile("global_load_dwordx4 %0, %1, off sc0 sc1" : "=v"(hq0) : "v"(hb) : "memory");
      asm volatile("global_load_dwordx4 %0, %1, off offset:1024 sc0 sc1" : "=v"(hq1) : "v"(hb) : "memory");
      asm volatile("global_load_dwordx4 %0, %1, off offset:2048 sc0 sc1" : "=v"(hq2) : "v"(hb) : "memory");
      asm volatile("global_load_dwordx4 %0, %1, off offset:3072 sc0 sc1" : "=v"(hq3) : "v"(hb) : "memory");
      asm volatile("global_load_dwordx4 %0, %1, off sc0 sc1" : "=v"(hq4) : "v"(hb2) : "memory");
      asm volatile("global_load_dwordx4 %0, %1, off offset:1024 sc0 sc1" : "=v"(hq5) : "v"(hb2) : "memory");
      asm volatile("global_load_dwordx4 %0, %1, off offset:2048 sc0 sc1" : "=v"(hq6) : "v"(hb2) : "memory");
      asm volatile("global_load_dwordx4 %0, %1, off offset:3072 sc0 sc1" : "=v"(hq7) : "v"(hb2) : "memory");
      asm volatile("s_waitcnt vmcnt(4)" ::: "memory");   // hq0..3 (+older) done
      __builtin_amdgcn_sched_barrier(0);
      // rows r = wid*8 + p; r&7 = p => swizzle = p<<4 (compile-time)
      *(uintx4*)&LDS[HH_OFF + (wid * 8 + 0) * 1024 + ((lane * 16) ^ 0)] = hq0;
      *(uintx4*)&LDS[HH_OFF + (wid * 8 + 1) * 1024 + ((lane * 16) ^ 16)] = hq1;
      *(uintx4*)&LDS[HH_OFF + (wid * 8 + 2) * 1024 + ((lane * 16) ^ 32)] = hq2;
      *(uintx4*)&LDS[HH_OFF + (wid * 8 + 3) * 1024 + ((lane * 16) ^ 48)] = hq3;
      asm volatile("s_waitcnt vmcnt(0)" ::: "memory");
      __builtin_amdgcn_sched_barrier(0);
      *(uintx4*)&LDS[HH_OFF + (wid * 8 + 4) * 1024 + ((lane * 16) ^ 64)] = hq4;
      *(uintx4*)&LDS[HH_OFF + (wid * 8 + 5) * 1024 + ((lane * 16) ^ 80)] = hq5;
      *(uintx4*)&LDS[HH_OFF + (wid * 8 + 6) * 1024 + ((lane * 16) ^ 96)] = hq6;
      *(uintx4*)&LDS[HH_OFF + (wid * 8 + 7) * 1024 + ((lane * 16) ^ 112)] = hq7;
    }
    __syncthreads();                                     // (b)
    // ======== WT <- wi_{t+1} (wi reads of step t finished before (b)) ========
    {
      const int base = WT_OFF + rA * 256;
      const int swp = (rA & 7) << 4;
      uintx4 lo = {w[0], w[1], w[2], w[3]};
      uintx4 hi = {w[4], w[5], w[6], w[7]};
      *(uintx4*)&LDS[base + ((pA * 32) ^ swp)] = lo;
      *(uintx4*)&LDS[base + ((pA * 32 + 16) ^ swp)] = hi;
    }
    // ======== h MFMAs: 8 A-reads feed 32 MFMAs ========
    if (t > 0) {
      const int rowA = rt * 16 + colB;
#pragma unroll
      for (int ksl = 0; ksl < 8; ++ksl) {
        const int k2 = kh * 512 + ksl * 64 + kg * 16;
        short8 aA = *(const short8*)&LDS[HH_OFF + rowA * 1024 + (k2 ^ swB)];
        acc[0] = __builtin_amdgcn_mfma_f32_16x16x32_bf16(aA, bh[ksl][0], acc[0], 0, 0, 0);
        acc[1] = __builtin_amdgcn_mfma_f32_16x16x32_bf16(aA, bh[ksl][1], acc[1], 0, 0, 0);
        acc[2] = __builtin_amdgcn_mfma_f32_16x16x32_bf16(aA, bh[ksl][2], acc[2], 0, 0, 0);
        acc[3] = __builtin_amdgcn_mfma_f32_16x16x32_bf16(aA, bh[ksl][3], acc[3], 0, 0, 0);
      }
    }
    // ======== kh=1: publish partials to GT ========
    if (kh == 1) {
#pragma unroll
      for (int ct = 0; ct < 4; ++ct)
#pragma unroll
        for (int r = 0; r < 4; ++r) {
          const int row = rt * 16 + kg * 4 + r;
          *(float*)&LDS[GT_OFF + (row * 66 + ct * 16 + colB) * 4] = acc[ct][r];
        }
    }
    __syncthreads();                                     // (c)
    if (kh == 0) {
      // ======== pointwise: 4 cells/lane, all gates local ========
      float hn[4];
      unsigned int mm[4];
#define PW(r, cvar)                                                            \
      {                                                                        \
        const int row = rt * 16 + kg * 4 + r;                                  \
        const float* g = (const float*)&LDS[GT_OFF + (row * 66 + colB) * 4];   \
        const float gi = acc[0][r] + g[0] + bi_i;                              \
        const float gf = acc[1][r] + g[16] + bi_f;                             \
        const float gg = acc[2][r] + g[32] + bi_g;                             \
        const float go = acc[3][r] + g[48] + bi_o;                             \
        const float cn = sigf(gf) * cvar + sigf(gi) * tanh_fast(gg);           \
        hn[r] = sigf(go) * tanh_fast(cn);                                      \
        cvar = cn;                                                             \
        mm[r] = (unsigned int)f2bf(hn[r]);                                     \
      }
      PW(0, c0) PW(1, c1) PW(2, c2) PW(3, c3)
#undef PW
      // ---- h hand-off: lane-pair packed 4B MALL stores ----
      unsigned int oo[4];
#pragma unroll
      for (int r = 0; r < 4; ++r) oo[r] = (unsigned int)__shfl_xor((int)mm[r], 1);
      if (!(lane & 1)) {
        unsigned short* hd0 = hbuf + (((t + 1) & 1) ? (size_t)(NB * NH) : 0);
#pragma unroll
        for (int r = 0; r < 4; ++r) {
          const int row = rt * 16 + kg * 4 + r;
          unsigned short* hp = hd0 + (size_t)(bb0 + row) * NH + jC2;
          const unsigned int dv = mm[r] | (oo[r] << 16);
          asm volatile("global_store_dword %0, %1, off sc0 sc1" :: "v"(hp), "v"(dv) : "memory");
        }
      }
      asm volatile("s_waitcnt vmcnt(0)" ::: "memory");   // own h stores ACK'd
      if (lane == 0) {
        unsigned int* fs = fblk + rt;                    // per-wave flag dword
        const unsigned int tv = (unsigned int)(t + 1);
        asm volatile("global_store_dword %0, %1, off sc0 sc1" :: "v"(fs), "v"(tv) : "memory");
      }
      // ---- out1 (off critical path) ----
#pragma unroll
      for (int r = 0; r < 4; ++r) {
        const int row = rt * 16 + kg * 4 + r;
        __builtin_nontemporal_store(hn[r],
            &out1[((size_t)(bb0 + row) * NT + t) * NH + jC2]);
      }
    } else if (wid == 4 && t + 1 < NT) {
      // ======== poll for step t+1 (overlaps producers' tails) ========
      const int tv = t + 1;
      uintx4 v;
      do {
        asm volatile("global_load_dwordx4 %0, %1, off sc0 sc1\n\ts_waitcnt vmcnt(0)"
                     : "=v"(v) : "v"(fpoll) : "memory");
      } while (!__all((int)v[0] >= tv && (int)v[1] >= tv &&
                      (int)v[2] >= tv && (int)v[3] >= tv));
    }
    // ======== x prefetch for t+2 ========
    {
      const int tx = (t + 2 < NT) ? (t + 2) : (NT - 1);
      const float* xs = xrow + (size_t)tx * ND;
#pragma unroll
      for (int q = 0; q < 4; ++q) xr4[q] = *(const floatx4*)(xs + 4 * q);
    }
    __syncthreads();                                     // (a)
  }
}

// ---------------------------------------------------------------------------
extern "C" void kernel_launch(void* const* d_in, const int* in_sizes, int n_in,
                              void* d_out, int out_size, void* d_ws, size_t ws_size,
                              hipStream_t stream) {
  (void)in_sizes; (void)n_in; (void)out_size; (void)ws_size;
  const float* in     = (const float*)d_in[0];
  const float* W_ih   = (const float*)d_in[1];
  const float* W_hh   = (const float*)d_in[2];
  const float* b_ih   = (const float*)d_in[3];
  const float* b_hh   = (const float*)d_in[4];
  const float* attn_W = (const float*)d_in[5];
  // d_in[6] (attn_b) cancels in the softmax -> unused.

  float* out0 = (float*)d_out;                          // (512,128,128)
  float* out1 = out0 + (size_t)NB * NT * ND;            // (512,128,512)

  float* attn_ws = (float*)d_ws;                                     // 256 KB
  unsigned short* hbuf = (unsigned short*)((char*)d_ws + 262144);    // 1 MB
  unsigned int* flags = (unsigned int*)((char*)d_ws + 262144 + 1048576); // 16 KB

  hipMemsetAsync(flags, 0, 16384, stream);
  attn_kernel<<<NB, 128, 0, stream>>>(in, attn_W, out0, attn_ws);
  rec_kernel<<<256, 512, 0, stream>>>(in, W_ih, W_hh, b_ih, b_hh, attn_ws,
                                      hbuf, flags, out1);
}

// Round 9
// 629.189 us; speedup vs baseline: 1.5218x; 1.5218x over previous
//
#include <hip/hip_runtime.h>

// B=512, T-1=128, D=128, H=512. softmax(proj_x + shift[:,None]) == softmax(proj_x)
// => attention is timestep-invariant; only the LSTM recurrence is sequential.
//
// R9 = R3's PROVEN skeleton (wave0 poll + (a), MALL sc0 sc1 hand-off, LDS-staged
// h, barriers (b)(c)(d), ping-pong hbuf, 1 block/CU) with:
//  (1) geometry 16 groups x 16 slices (block = 32 rows x 32 h-cols): halves
//      h-gather MALL BW (16->8 MB/step), halves poll degree (16 flags).
//  (2) wi-pack + x-prefetch moved into the h-load latency shadow.
//  (3) v_cvt_pk_bf16_f32 for hot bf16 packing.
// Register audit: bh 128 + hq 16 + acc 16 + misc ~40 => ~200 <= 256 (no spill;
// R5's regression was ~272-reg spill, detectable via FETCH_SIZE).

typedef __attribute__((ext_vector_type(8))) short short8;
typedef __attribute__((ext_vector_type(4))) float floatx4;
typedef __attribute__((ext_vector_type(4))) unsigned int uintx4;

#define NB 512
#define NT 128
#define ND 128
#define NH 512

// LDS layout (107008 B total; >81920 => 1 block/CU, sync co-residency holds)
#define WI_OFF 0        // W_ih slice [128][128] bf16 swizzled (32 KB)
#define WT_OFF 32768    // wi tile [32][128] bf16 swizzled (8 KB)
#define HH_OFF 40960    // h tile [32][512] bf16 swizzled (32 KB)
#define GT_OFF 73728    // gates [2 kh][32][130] f32 (33280 B)
#define GT_PL  16640
#define LDS_BYTES 107008

static __device__ __forceinline__ unsigned short f2bf(float f) {
  unsigned int u = __float_as_uint(f);
  u += 0x7fffu + ((u >> 16) & 1u);   // RNE
  return (unsigned short)(u >> 16);
}
static __device__ __forceinline__ unsigned int cvtpk(float lo, float hi) {
  unsigned int r;
  asm("v_cvt_pk_bf16_f32 %0, %1, %2" : "=v"(r) : "v"(lo), "v"(hi));
  return r;
}
static __device__ __forceinline__ float sigf(float x) {
  return 1.f / (1.f + __expf(-x));
}
static __device__ __forceinline__ float tanh_fast(float x) {
  const float e = __expf(-2.f * fabsf(x));
  const float r = (1.f - e) / (1.f + e);
  return copysignf(r, x);
}

// ---------------------------------------------------------------------------
// Kernel A: attn[b,d] = softmax_d( sum_t in[b,t,d]*wx[t] ); out0 = attn*in
// ---------------------------------------------------------------------------
__global__ __launch_bounds__(128) void attn_kernel(
    const float* __restrict__ in, const float* __restrict__ attn_W,
    float* __restrict__ out0, float* __restrict__ attn_ws) {
  const int b = blockIdx.x;
  const int d = threadIdx.x;
  __shared__ float wx[NT];
  __shared__ float red[4];
  wx[d] = attn_W[2 * NH + d];
  __syncthreads();
  const float* ib = in + (size_t)b * (NT * ND);
  float p = 0.f;
#pragma unroll 8
  for (int t = 0; t < NT; ++t) p = fmaf(ib[t * ND + d], wx[t], p);
  float m = p;
#pragma unroll
  for (int off = 32; off >= 1; off >>= 1) m = fmaxf(m, __shfl_xor(m, off));
  const int wv = d >> 6;
  if ((d & 63) == 0) red[wv] = m;
  __syncthreads();
  const float M = fmaxf(red[0], red[1]);
  const float e = expf(p - M);
  float s = e;
#pragma unroll
  for (int off = 32; off >= 1; off >>= 1) s += __shfl_xor(s, off);
  if ((d & 63) == 0) red[2 + wv] = s;
  __syncthreads();
  const float a = e / (red[2] + red[3]);
  attn_ws[b * ND + d] = a;
#pragma unroll 4
  for (int t = 0; t < NT; ++t)
    out0[(size_t)b * (NT * ND) + t * ND + d] = a * ib[t * ND + d];
}

// ---------------------------------------------------------------------------
// Kernel C: persistent fused LSTM recurrence. 256 blocks x 512 thr, 1/CU.
// Block (gid=bid&15, sid=bid>>4): batch rows [gid*32,+32), h-cols [sid*32,+32).
// Wave wid: rw=wid&1 (16-row half), cg=(wid>>1)&1 (gate pair), kh=wid>>2 (K half).
// Per wave: 4 B-frag sets (2 gates x 2 col-halves) -> bh[8][4] in regs;
// W_ih B-frags from LDS tile; acc[4] (16 f32).
// ---------------------------------------------------------------------------
__global__ __launch_bounds__(512, 2) void rec_kernel(
    const float* __restrict__ in, const float* __restrict__ W_ih,
    const float* __restrict__ W_hh, const float* __restrict__ b_ih,
    const float* __restrict__ b_hh, const float* __restrict__ attn_ws,
    unsigned short* __restrict__ hbuf, unsigned int* __restrict__ flags,
    float* __restrict__ out1) {
  __shared__ __align__(16) unsigned char LDS[LDS_BYTES];
  const int tid = threadIdx.x;
  const int bid = blockIdx.x;
  const int gid = bid & 15;
  const int sid = bid >> 4;
  const int bb0 = gid * 32;
  const int n0 = sid * 32;
  const int lane = tid & 63;
  const int wid = tid >> 6;
  const int rw = wid & 1;
  const int cg = (wid >> 1) & 1;
  const int kh = wid >> 2;
  const int colB = lane & 15;
  const int kg = lane >> 4;
  const int swB = (colB & 7) << 4;

  // ---- W_hh fragments -> registers (128 regs) ----
  short8 bh[8][4];
#pragma unroll
  for (int j = 0; j < 4; ++j) {
    const int gate = cg * 2 + (j >> 1);
    const int cc = (j & 1) * 16 + colB;
    const float* wr = W_hh + (size_t)(gate * NH + n0 + cc) * NH + kh * 256;
#pragma unroll
    for (int ksl = 0; ksl < 8; ++ksl) {
      const int k0 = ksl * 32 + kg * 8;
      floatx4 f0 = *(const floatx4*)(wr + k0);
      floatx4 f1 = *(const floatx4*)(wr + k0 + 4);
      short8 s;
#pragma unroll
      for (int i = 0; i < 4; ++i) {
        s[i] = (short)f2bf(f0[i]);
        s[4 + i] = (short)f2bf(f1[i]);
      }
      bh[ksl][j] = s;
    }
  }
  // ---- W_ih slice -> LDS tile [128 gate-rows][128 k] bf16 swizzled ----
#pragma unroll 8
  for (int it = 0; it < 32; ++it) {
    const int row = it * 4 + (tid >> 7);           // 0..127 = gate*32 + c
    const int k = tid & 127;
    const int gate = row >> 5;
    const int cc = row & 31;
    *(unsigned short*)&LDS[WI_OFF + row * 256 + ((2 * k) ^ ((row & 7) << 4))] =
        f2bf(W_ih[(size_t)(gate * NH + n0 + cc) * ND + k]);
  }

  // ---- attention packed bf16 (t-invariant) ----
  const int rA = tid >> 4;          // staging/pointwise row 0..31
  const int pA = tid & 15;          // 8-float chunk 0..15
  unsigned int apk[4];
  {
    const float* ap = attn_ws + (size_t)(bb0 + rA) * ND + pA * 8;
#pragma unroll
    for (int p = 0; p < 4; ++p)
      apk[p] = (unsigned int)f2bf(ap[2 * p]) |
               ((unsigned int)f2bf(ap[2 * p + 1]) << 16);
  }
  // ---- biases (pointwise cells: (prow=rA, cols colC and colC+16)) ----
  const int prow = rA;
  const int colC = pA;
  float biA[4], biB[4];
#pragma unroll
  for (int g = 0; g < 4; ++g) {
    biA[g] = b_ih[g * NH + n0 + colC] + b_hh[g * NH + n0 + colC];
    biB[g] = b_ih[g * NH + n0 + colC + 16] + b_hh[g * NH + n0 + colC + 16];
  }
  float cA = 0.f, cB = 0.f;

  unsigned int* fslot = flags + (gid * 16 + sid) * 16;
  const unsigned int* fpoll = flags + (gid * 16 + (lane & 15)) * 16;
  const float* xrow = in + (size_t)(bb0 + rA) * (NT * ND) + pA * 8;

  // ---- prologue: WT <- wi_0; (xa,xb) <- x_1 ----
  floatx4 xa = *(const floatx4*)(xrow);
  floatx4 xb = *(const floatx4*)(xrow + 4);
  {
    unsigned int w0 = cvtpk(__uint_as_float(apk[0] << 16) * xa[0],
                            __uint_as_float(apk[0] & 0xffff0000u) * xa[1]);
    unsigned int w1 = cvtpk(__uint_as_float(apk[1] << 16) * xa[2],
                            __uint_as_float(apk[1] & 0xffff0000u) * xa[3]);
    unsigned int w2 = cvtpk(__uint_as_float(apk[2] << 16) * xb[0],
                            __uint_as_float(apk[2] & 0xffff0000u) * xb[1]);
    unsigned int w3 = cvtpk(__uint_as_float(apk[3] << 16) * xb[2],
                            __uint_as_float(apk[3] & 0xffff0000u) * xb[3]);
    uintx4 wv = {w0, w1, w2, w3};
    *(uintx4*)&LDS[WT_OFF + rA * 256 + ((pA * 16) ^ ((rA & 7) << 4))] = wv;
  }
  xa = *(const floatx4*)(xrow + ND);
  xb = *(const floatx4*)(xrow + ND + 4);
  __syncthreads();

  for (int t = 0; t < NT; ++t) {
    floatx4 acc[4];
#pragma unroll
    for (int j = 0; j < 4; ++j) acc[j] = {0.f, 0.f, 0.f, 0.f};
    unsigned int w0, w1, w2, w3;

    if (t > 0) {
      // ---- group sync: wave0 polls the 16 flags (MALL-coherent) ----
      if (wid == 0) {
        unsigned int v;
        do {
          asm volatile("global_load_dword %0, %1, off sc0 sc1\n\ts_waitcnt vmcnt(0)"
                       : "=v"(v) : "v"(fpoll) : "memory");
        } while (!__all((int)v >= t));
      }
      __syncthreads();                                   // (a)
      // ---- issue h-tile gather (rows p*8+wid, 1KB coalesced per load) ----
      const unsigned short* hb = hbuf + ((t & 1) ? (size_t)(NB * NH) : 0);
      const unsigned short* s0 = hb + (size_t)(bb0 + 0 * 8 + wid) * NH + lane * 8;
      const unsigned short* s1 = hb + (size_t)(bb0 + 1 * 8 + wid) * NH + lane * 8;
      const unsigned short* s2 = hb + (size_t)(bb0 + 2 * 8 + wid) * NH + lane * 8;
      const unsigned short* s3 = hb + (size_t)(bb0 + 3 * 8 + wid) * NH + lane * 8;
      uintx4 hq0, hq1, hq2, hq3;
      asm volatile("global_load_dwordx4 %0, %1, off sc0 sc1" : "=v"(hq0) : "v"(s0) : "memory");
      asm volatile("global_load_dwordx4 %0, %1, off sc0 sc1" : "=v"(hq1) : "v"(s1) : "memory");
      asm volatile("global_load_dwordx4 %0, %1, off sc0 sc1" : "=v"(hq2) : "v"(s2) : "memory");
      asm volatile("global_load_dwordx4 %0, %1, off sc0 sc1" : "=v"(hq3) : "v"(s3) : "memory");
      // ---- in the load shadow: pack wi_{t+1}, prefetch x_{t+2}, wi MFMAs ----
      w0 = cvtpk(__uint_as_float(apk[0] << 16) * xa[0],
                 __uint_as_float(apk[0] & 0xffff0000u) * xa[1]);
      w1 = cvtpk(__uint_as_float(apk[1] << 16) * xa[2],
                 __uint_as_float(apk[1] & 0xffff0000u) * xa[3]);
      w2 = cvtpk(__uint_as_float(apk[2] << 16) * xb[0],
                 __uint_as_float(apk[2] & 0xffff0000u) * xb[1]);
      w3 = cvtpk(__uint_as_float(apk[3] << 16) * xb[2],
                 __uint_as_float(apk[3] & 0xffff0000u) * xb[3]);
      {
        const int tx = (t + 2 < NT) ? (t + 2) : (NT - 1);
        xa = *(const floatx4*)(xrow + (size_t)tx * ND);
        xb = *(const floatx4*)(xrow + (size_t)tx * ND + 4);
      }
#pragma unroll
      for (int ksl = 0; ksl < 2; ++ksl) {
        const int k2 = kh * 128 + ksl * 64 + kg * 16;
        short8 aA = *(const short8*)&LDS[WT_OFF + (rw * 16 + colB) * 256 + (k2 ^ swB)];
#pragma unroll
        for (int j = 0; j < 4; ++j) {
          const int br = (cg * 2 + (j >> 1)) * 32 + (j & 1) * 16 + colB;
          short8 bf = *(const short8*)&LDS[WI_OFF + br * 256 + (k2 ^ swB)];
          acc[j] = __builtin_amdgcn_mfma_f32_16x16x32_bf16(aA, bf, acc[j], 0, 0, 0);
        }
      }
      asm volatile("s_waitcnt vmcnt(0)" ::: "memory");
      __builtin_amdgcn_sched_barrier(0);
      // rows r = p*8+wid => r&7 = wid => swizzle (wid<<4)
      *(uintx4*)&LDS[HH_OFF + (0 * 8 + wid) * 1024 + ((lane * 16) ^ (wid << 4))] = hq0;
      *(uintx4*)&LDS[HH_OFF + (1 * 8 + wid) * 1024 + ((lane * 16) ^ (wid << 4))] = hq1;
      *(uintx4*)&LDS[HH_OFF + (2 * 8 + wid) * 1024 + ((lane * 16) ^ (wid << 4))] = hq2;
      *(uintx4*)&LDS[HH_OFF + (3 * 8 + wid) * 1024 + ((lane * 16) ^ (wid << 4))] = hq3;
      __syncthreads();                                   // (b)
      // ---- WT <- wi_{t+1} (step-t WT reads finished before (b)) ----
      {
        uintx4 wv = {w0, w1, w2, w3};
        *(uintx4*)&LDS[WT_OFF + rA * 256 + ((pA * 16) ^ ((rA & 7) << 4))] = wv;
      }
      // ---- h MFMAs: 8 A-reads feed 32 MFMAs ----
#pragma unroll
      for (int ksl = 0; ksl < 8; ++ksl) {
        const int k2 = kh * 512 + ksl * 64 + kg * 16;
        short8 aA = *(const short8*)&LDS[HH_OFF + (rw * 16 + colB) * 1024 + (k2 ^ swB)];
        acc[0] = __builtin_amdgcn_mfma_f32_16x16x32_bf16(aA, bh[ksl][0], acc[0], 0, 0, 0);
        acc[1] = __builtin_amdgcn_mfma_f32_16x16x32_bf16(aA, bh[ksl][1], acc[1], 0, 0, 0);
        acc[2] = __builtin_amdgcn_mfma_f32_16x16x32_bf16(aA, bh[ksl][2], acc[2], 0, 0, 0);
        acc[3] = __builtin_amdgcn_mfma_f32_16x16x32_bf16(aA, bh[ksl][3], acc[3], 0, 0, 0);
      }
    } else {
      // t == 0: wi only
#pragma unroll
      for (int ksl = 0; ksl < 2; ++ksl) {
        const int k2 = kh * 128 + ksl * 64 + kg * 16;
        short8 aA = *(const short8*)&LDS[WT_OFF + (rw * 16 + colB) * 256 + (k2 ^ swB)];
#pragma unroll
        for (int j = 0; j < 4; ++j) {
          const int br = (cg * 2 + (j >> 1)) * 32 + (j & 1) * 16 + colB;
          short8 bf = *(const short8*)&LDS[WI_OFF + br * 256 + (k2 ^ swB)];
          acc[j] = __builtin_amdgcn_mfma_f32_16x16x32_bf16(aA, bf, acc[j], 0, 0, 0);
        }
      }
      w0 = cvtpk(__uint_as_float(apk[0] << 16) * xa[0],
                 __uint_as_float(apk[0] & 0xffff0000u) * xa[1]);
      w1 = cvtpk(__uint_as_float(apk[1] << 16) * xa[2],
                 __uint_as_float(apk[1] & 0xffff0000u) * xa[3]);
      w2 = cvtpk(__uint_as_float(apk[2] << 16) * xb[0],
                 __uint_as_float(apk[2] & 0xffff0000u) * xb[1]);
      w3 = cvtpk(__uint_as_float(apk[3] << 16) * xb[2],
                 __uint_as_float(apk[3] & 0xffff0000u) * xb[3]);
      xa = *(const floatx4*)(xrow + 2 * ND);
      xb = *(const floatx4*)(xrow + 2 * ND + 4);
      __syncthreads();                                   // (b)
      {
        uintx4 wv = {w0, w1, w2, w3};
        *(uintx4*)&LDS[WT_OFF + rA * 256 + ((pA * 16) ^ ((rA & 7) << 4))] = wv;
      }
    }
    // ---- gate partials -> GT[kh][32][130] ----
#pragma unroll
    for (int j = 0; j < 4; ++j) {
      const int gc = (cg * 2 + (j >> 1)) * 32 + (j & 1) * 16 + colB;
#pragma unroll
      for (int r = 0; r < 4; ++r) {
        const int row = rw * 16 + kg * 4 + r;   // C layout: row=(lane>>4)*4+reg
        *(float*)&LDS[GT_OFF + kh * GT_PL + (row * 130 + gc) * 4] = acc[j][r];
      }
    }
    __syncthreads();                                     // (c)
    // ---- LSTM pointwise: 2 cells/thread (cols colC, colC+16 of row prow) ----
    float hnA, hnB;
    {
      const float* g0 = (const float*)&LDS[GT_OFF + prow * 130 * 4];
      const float* g1 = (const float*)&LDS[GT_OFF + GT_PL + prow * 130 * 4];
      {
        const float gi = g0[colC] + g1[colC] + biA[0];
        const float gf = g0[32 + colC] + g1[32 + colC] + biA[1];
        const float gg = g0[64 + colC] + g1[64 + colC] + biA[2];
        const float go = g0[96 + colC] + g1[96 + colC] + biA[3];
        const float cn = sigf(gf) * cA + sigf(gi) * tanh_fast(gg);
        hnA = sigf(go) * tanh_fast(cn);
        cA = cn;
      }
      {
        const float gi = g0[16 + colC] + g1[16 + colC] + biB[0];
        const float gf = g0[48 + colC] + g1[48 + colC] + biB[1];
        const float gg = g0[80 + colC] + g1[80 + colC] + biB[2];
        const float go = g0[112 + colC] + g1[112 + colC] + biB[3];
        const float cn = sigf(gf) * cB + sigf(gi) * tanh_fast(gg);
        hnB = sigf(go) * tanh_fast(cn);
        cB = cn;
      }
    }
    // ---- h hand-off: lane-pair cvt_pk -> 4B MALL stores ----
    const float oA = __shfl_xor(hnA, 1);
    const float oB = __shfl_xor(hnB, 1);
    if (!(lane & 1)) {
      unsigned short* hd = hbuf + (((t + 1) & 1) ? (size_t)(NB * NH) : 0) +
                           (size_t)(bb0 + prow) * NH + n0;
      unsigned short* pAp = hd + colC;
      unsigned short* pBp = hd + colC + 16;
      const unsigned int dA = cvtpk(hnA, oA);
      const unsigned int dB = cvtpk(hnB, oB);
      asm volatile("global_store_dword %0, %1, off sc0 sc1" :: "v"(pAp), "v"(dA) : "memory");
      asm volatile("global_store_dword %0, %1, off sc0 sc1" :: "v"(pBp), "v"(dB) : "memory");
    }
    asm volatile("s_waitcnt vmcnt(0)" ::: "memory");     // h stores ACK'd at MALL
    __syncthreads();                                     // (d)
    if (tid == 0) {
      const unsigned int tv = (unsigned int)(t + 1);
      asm volatile("global_store_dword %0, %1, off sc0 sc1" :: "v"(fslot), "v"(tv) : "memory");
    }
    // ---- off-critical-path out1 stores ----
    __builtin_nontemporal_store(hnA,
        &out1[((size_t)(bb0 + prow) * NT + t) * NH + n0 + colC]);
    __builtin_nontemporal_store(hnB,
        &out1[((size_t)(bb0 + prow) * NT + t) * NH + n0 + colC + 16]);
  }
}

// ---------------------------------------------------------------------------
extern "C" void kernel_launch(void* const* d_in, const int* in_sizes, int n_in,
                              void* d_out, int out_size, void* d_ws, size_t ws_size,
                              hipStream_t stream) {
  (void)in_sizes; (void)n_in; (void)out_size; (void)ws_size;
  const float* in     = (const float*)d_in[0];
  const float* W_ih   = (const float*)d_in[1];
  const float* W_hh   = (const float*)d_in[2];
  const float* b_ih   = (const float*)d_in[3];
  const float* b_hh   = (const float*)d_in[4];
  const float* attn_W = (const float*)d_in[5];
  // d_in[6] (attn_b) cancels in the softmax -> unused.

  float* out0 = (float*)d_out;                          // (512,128,128)
  float* out1 = out0 + (size_t)NB * NT * ND;            // (512,128,512)

  float* attn_ws = (float*)d_ws;                                     // 256 KB
  unsigned short* hbuf = (unsigned short*)((char*)d_ws + 262144);    // 1 MB
  unsigned int* flags = (unsigned int*)((char*)d_ws + 262144 + 1048576); // 16 KB

  hipMemsetAsync(flags, 0, 16384, stream);
  attn_kernel<<<NB, 128, 0, stream>>>(in, attn_W, out0, attn_ws);
  rec_kernel<<<256, 512, 0, stream>>>(in, W_ih, W_hh, b_ih, b_hh, attn_ws,
                                      hbuf, flags, out1);
}